// Round 8
// baseline (153.342 us; speedup 1.0000x reference)
//
#include <hip/hip_runtime.h>

#define BB 8
#define TT 2048
#define CC 1024
#define HH 64
#define MM (BB * TT)   // 16384 rows

typedef _Float16 half8 __attribute__((ext_vector_type(8)));
typedef _Float16 half4 __attribute__((ext_vector_type(4)));
typedef float floatx4 __attribute__((ext_vector_type(4)));

// async global->LDS, 16 B per lane (LDS dest = wave-uniform base + lane*16)
__device__ __forceinline__ void gload_lds16(const void* g, void* l)
{
    __builtin_amdgcn_global_load_lds(
        (const __attribute__((address_space(1))) unsigned int*)g,
        (__attribute__((address_space(3))) unsigned int*)l, 16, 0, 0);
}

// 16-lane all-reduce max via DPP row-rotate butterfly (VALU pipe, no LDS).
template <int CTRL>
__device__ __forceinline__ float dpp_max_step(float x)
{
    union { float f; int i; } u, v;
    u.f = x;
    v.i = __builtin_amdgcn_update_dpp(u.i, u.i, CTRL, 0xf, 0xf, false);
    return fmaxf(x, v.f);
}
__device__ __forceinline__ float rowmax16(float x)
{
    x = dpp_max_step<0x128>(x);   // ROW_ROR:8
    x = dpp_max_step<0x124>(x);   // ROW_ROR:4
    x = dpp_max_step<0x122>(x);   // ROW_ROR:2
    x = dpp_max_step<0x121>(x);   // ROW_ROR:1
    return x;
}

// ---------------------------------------------------------------------------
// Kernel 0: pack W chunk-major: Wp[(c*192+row)*32+kk] = Wsc[row][c*32+kk].
// rows 0..63 = Wq*8 (sqrt(H) fold), 64..127 = Wk, 128..191 = Wv.
// A 16x16x32 B-fragment is contiguous 1 KB.
// ---------------------------------------------------------------------------
__global__ __launch_bounds__(256)
void w_pack(const float* __restrict__ Wk, const float* __restrict__ Wq,
            const float* __restrict__ Wv, _Float16* __restrict__ Wp)
{
    const int idx = (blockIdx.x * 256 + threadIdx.x) * 8;
    const int c   = idx / 6144;
    const int rm  = idx - c * 6144;
    const int row = rm >> 5;
    const int kk  = rm & 31;
    const int which = row >> 6;
    const float* __restrict__ src = (which == 0) ? Wq : ((which == 1) ? Wk : Wv);
    const float scale = (which == 0) ? 8.0f : 1.0f;
    const int srow = row & 63;
    const int k = c * 32 + kk;
    const float4 a = *reinterpret_cast<const float4*>(&src[srow * 1024 + k]);
    const float4 b = *reinterpret_cast<const float4*>(&src[srow * 1024 + k + 4]);
    const half8 o = { (_Float16)(a.x * scale), (_Float16)(a.y * scale),
                      (_Float16)(a.z * scale), (_Float16)(a.w * scale),
                      (_Float16)(b.x * scale), (_Float16)(b.y * scale),
                      (_Float16)(b.z * scale), (_Float16)(b.w * scale) };
    *reinterpret_cast<half8*>(&Wp[idx]) = o;
}

// ---------------------------------------------------------------------------
// Kernel 1: QKV projection, m97-style. 512 blocks (64-row M x 96-col N half)
// x 256 thr (4 waves, wave = 16 rows x 96 cols, 6 acc frags).
// x staged fp32 via global_load_lds into double-buffered LDS with XOR granule
// swizzle (pos p of row r holds global granule p^(r&7)) -> A-frag ds_reads
// are 2-way (free). W frags register-prefetched one chunk ahead (the barrier
// drains them for free). Outputs: q16 row-major; Kp/Vp fragment-packed with
// the SAME XOR swizzle baked in so attn can stage them with identity
// global_load_lds and conflict-free ds_reads.
//   Kp frag f = nt*2 + (h/32)  (nt = key64/16); granule g = (key%16)*4 +
//     (h%32)/8 stored at g^((g>>3)&7), half j = h%8
//   Vp frag f = (h/16)*2 + (key64/32); g = (h%16)*4 + (key%32)/8 swizzled,
//     j = key%8
// ---------------------------------------------------------------------------
__global__ __launch_bounds__(256, 3)
void qkv8(const float* __restrict__ x, const _Float16* __restrict__ Wp,
          _Float16* __restrict__ q16, _Float16* __restrict__ Kp,
          _Float16* __restrict__ Vp)
{
    __shared__ float Xs[2][64 * 32];   // 2 x 8 KB

    const int tid  = threadIdx.x;
    const int lane = tid & 63;
    const int wv   = tid >> 6;
    const int m_base = (blockIdx.x >> 1) * 64;
    const int nbase  = (blockIdx.x & 1) * 96;
    const int fm = lane & 15;
    const int fq = lane >> 4;
    const int fk = fq * 8;
    const int fr = fq * 4;

    // staging: 2 instrs/wave, instr i covers rows wv*16 + i*8 + (lane>>3)
    const int srow = wv * 16 + (lane >> 3);
    const int gg   = (lane & 7) ^ (lane >> 3);   // swizzled global granule
    const float* __restrict__ gx0 = &x[(size_t)(m_base + srow) * CC + gg * 4];

    const _Float16* __restrict__ wbase = &Wp[(nbase + fm) * 32 + fk];

    floatx4 acc[6];
    #pragma unroll
    for (int n = 0; n < 6; ++n)
        #pragma unroll
        for (int r = 0; r < 4; ++r) acc[n][r] = 0.0f;

    half8 wf[6], wfn[6];

    // prologue: stage chunk 0, load W chunk 0
    gload_lds16(gx0,            &Xs[0][(wv * 2 + 0) * 256]);
    gload_lds16(gx0 + 8 * CC,   &Xs[0][(wv * 2 + 1) * 256]);
    #pragma unroll
    for (int n = 0; n < 6; ++n)
        wf[n] = *reinterpret_cast<const half8*>(wbase + n * 512);

    // A-frag read coords (swizzled)
    const int arow = wv * 16 + fm;
    const int p0 = ((2 * fq) ^ (fm & 7)) * 4;
    const int p1 = ((2 * fq + 1) ^ (fm & 7)) * 4;

    for (int c = 0; c < 32; ++c) {
        const int cur = c & 1;
        __syncthreads();                       // drains chunk c's async loads
        if (c + 1 < 32) {                      // issue chunk c+1 (in flight during compute)
            const float* gx = gx0 + (c + 1) * 32;
            gload_lds16(gx,          &Xs[1 - cur][(wv * 2 + 0) * 256]);
            gload_lds16(gx + 8 * CC, &Xs[1 - cur][(wv * 2 + 1) * 256]);
            const _Float16* wc = wbase + (c + 1) * 6144;
            #pragma unroll
            for (int n = 0; n < 6; ++n)
                wfn[n] = *reinterpret_cast<const half8*>(wc + n * 512);
        }
        const float4 a0 = *reinterpret_cast<const float4*>(&Xs[cur][arow * 32 + p0]);
        const float4 a1 = *reinterpret_cast<const float4*>(&Xs[cur][arow * 32 + p1]);
        const half8 af = { (_Float16)a0.x, (_Float16)a0.y, (_Float16)a0.z, (_Float16)a0.w,
                           (_Float16)a1.x, (_Float16)a1.y, (_Float16)a1.z, (_Float16)a1.w };
        #pragma unroll
        for (int n = 0; n < 6; ++n)
            acc[n] = __builtin_amdgcn_mfma_f32_16x16x32_f16(af, wf[n], acc[n], 0, 0, 0);
        if (c + 1 < 32) {
            #pragma unroll
            for (int n = 0; n < 6; ++n) wf[n] = wfn[n];
        }
    }

    // epilogue
    const size_t bt = (size_t)(m_base >> 6) * 8;     // frag base of this 64-key tile
    #pragma unroll
    for (int n = 0; n < 6; ++n) {
        const int col = nbase + n * 16 + fm;
        if (col < 64) {                              // q row-major
            #pragma unroll
            for (int r = 0; r < 4; ++r)
                q16[(size_t)(m_base + wv * 16 + fr + r) * HH + col] = (_Float16)acc[n][r];
        } else if (col < 128) {                      // K fragment-packed + swizzle
            const int h = col - 64;
            const int f = wv * 2 + (h >> 5);
            const int j = h & 7;
            #pragma unroll
            for (int r = 0; r < 4; ++r) {
                const int kl = fr + r;               // key within frag (0..15)
                const int g  = kl * 4 + ((h & 31) >> 3);
                const int sg = g ^ ((g >> 3) & 7);
                Kp[(bt + f) * 512 + sg * 8 + j] = (_Float16)acc[n][r];
            }
        } else {                                     // V fragment-packed + swizzle
            const int h   = col - 128;
            const int klq = wv * 16 + fr;            // first key of quad (0..63)
            const int f   = (h >> 4) * 2 + (klq >> 5);
            const int g   = (h & 15) * 4 + ((klq & 31) >> 3);
            const int sg  = g ^ ((g >> 3) & 7);
            const int j0  = klq & 7;                 // 0 or 4
            const half4 pk = { (_Float16)acc[n][0], (_Float16)acc[n][1],
                               (_Float16)acc[n][2], (_Float16)acc[n][3] };
            *reinterpret_cast<half4*>(&Vp[(bt + f) * 512 + sg * 8 + j0]) = pk;
        }
    }
}

// ---------------------------------------------------------------------------
// Kernel 2: m97-style split-K causal attention. 768 blocks = 32 q-tiles(64)
// x 8 batches x 3 segments (longest-first), 256 thr = 4 waves (16 q-rows
// each). K/V tiles staged via identity global_load_lds from packed Kp/Vp,
// double-buffered; loads for step j+1 issued right after the barrier ->
// in flight during all of step j's compute. Swizzled ds_reads (2-way, free).
// DPP row-max + ones-MFMA row-sum; split partials + combine.
// ---------------------------------------------------------------------------
__global__ __launch_bounds__(256, 3)
void attn8(const _Float16* __restrict__ q16, const _Float16* __restrict__ Kp,
           const _Float16* __restrict__ Vp, float* __restrict__ out,
           _Float16* __restrict__ Op, float* __restrict__ ml)
{
    __shared__ _Float16 Kb[2][8 * 512];   // 2 x 8 KB
    __shared__ _Float16 Vb[2][8 * 512];   // 2 x 8 KB
    __shared__ _Float16 Ps[4][16 * 68];

    const int bid = blockIdx.x;           // 0..767
    const int it  = 31 - bid / 24;        // longest q-tiles first
    const int sub = bid - (31 - it) * 24;
    const int b   = sub & 7;
    const int s   = sub >> 3;             // segment 0..2

    const int tid  = threadIdx.x;
    const int lane = tid & 63;
    const int wv   = tid >> 6;
    const int fm = lane & 15;
    const int fq = lane >> 4;
    const int fk = fq * 8;
    const int fr = fq * 4;

    const int Ji = it + 1;                // 64-key tiles in causal range
    const int qq = Ji / 3, rem = Ji - qq * 3;
    const int cnt   = qq + (s < rem ? 1 : 0);
    const int start = s * qq + (s < rem ? s : rem);

    const _Float16* __restrict__ kpb = Kp + (size_t)(b * 32) * 4096;
    const _Float16* __restrict__ vpb = Vp + (size_t)(b * 32) * 4096;

    const int qrow = b * TT + it * 64 + wv * 16 + fm;
    const half8 qf0 = *reinterpret_cast<const half8*>(&q16[(size_t)qrow * HH + fk]);
    const half8 qf1 = *reinterpret_cast<const half8*>(&q16[(size_t)qrow * HH + 32 + fk]);

    floatx4 O[4], lacc;
    float m_r[4];
    #pragma unroll
    for (int r = 0; r < 4; ++r) {
        m_r[r] = -3.0e38f;
        lacc[r] = 0.0f;
        #pragma unroll
        for (int ht = 0; ht < 4; ++ht) O[ht][r] = 0.0f;
    }
    const half8 ones = { (_Float16)1.f, (_Float16)1.f, (_Float16)1.f, (_Float16)1.f,
                         (_Float16)1.f, (_Float16)1.f, (_Float16)1.f, (_Float16)1.f };

    // swizzled B-frag read offset (halves)
    const int gQ = fm * 4 + fq;
    const int pQ = (gQ ^ ((gQ >> 3) & 7)) * 8;

    // prologue: stage first tile into buf 0 (wave wv stages frags 2wv,2wv+1)
    if (cnt > 0) {
        const size_t tb = (size_t)start * 4096;
        gload_lds16(kpb + tb + (2 * wv + 0) * 512 + lane * 8, &Kb[0][(2 * wv + 0) * 512]);
        gload_lds16(kpb + tb + (2 * wv + 1) * 512 + lane * 8, &Kb[0][(2 * wv + 1) * 512]);
        gload_lds16(vpb + tb + (2 * wv + 0) * 512 + lane * 8, &Vb[0][(2 * wv + 0) * 512]);
        gload_lds16(vpb + tb + (2 * wv + 1) * 512 + lane * 8, &Vb[0][(2 * wv + 1) * 512]);
    }

    for (int js = 0; js < cnt; ++js) {
        const int jj  = start + js;
        const int cur = js & 1;
        __syncthreads();                  // drains this step's staged loads
        if (js + 1 < cnt) {               // issue next tile (flies during compute)
            const size_t tb = (size_t)(jj + 1) * 4096;
            gload_lds16(kpb + tb + (2 * wv + 0) * 512 + lane * 8, &Kb[1 - cur][(2 * wv + 0) * 512]);
            gload_lds16(kpb + tb + (2 * wv + 1) * 512 + lane * 8, &Kb[1 - cur][(2 * wv + 1) * 512]);
            gload_lds16(vpb + tb + (2 * wv + 0) * 512 + lane * 8, &Vb[1 - cur][(2 * wv + 0) * 512]);
            gload_lds16(vpb + tb + (2 * wv + 1) * 512 + lane * 8, &Vb[1 - cur][(2 * wv + 1) * 512]);
        }

        // ---- S = Q K^T : 8 MFMAs, B-frags from LDS (swizzled, conflict-free)
        floatx4 sa[4];
        #pragma unroll
        for (int nt = 0; nt < 4; ++nt) {
            #pragma unroll
            for (int r = 0; r < 4; ++r) sa[nt][r] = 0.0f;
            const half8 b0 = *reinterpret_cast<const half8*>(&Kb[cur][(nt * 2 + 0) * 512 + pQ]);
            const half8 b1 = *reinterpret_cast<const half8*>(&Kb[cur][(nt * 2 + 1) * 512 + pQ]);
            sa[nt] = __builtin_amdgcn_mfma_f32_16x16x32_f16(qf0, b0, sa[nt], 0, 0, 0);
            sa[nt] = __builtin_amdgcn_mfma_f32_16x16x32_f16(qf1, b1, sa[nt], 0, 0, 0);
        }

        // ---- causal mask (only the diagonal tile) ----
        if (jj == it) {
            const int rbase = it * 64 + wv * 16 + fr;
            #pragma unroll
            for (int nt = 0; nt < 4; ++nt) {
                const int col = jj * 64 + nt * 16 + fm;
                #pragma unroll
                for (int r = 0; r < 4; ++r)
                    if (col > rbase + r) sa[nt][r] = -3.0e38f;
            }
        }

        // ---- online softmax: DPP row-max; row-sum via ones-MFMA ----
        #pragma unroll
        for (int r = 0; r < 4; ++r) {
            float mx = fmaxf(fmaxf(sa[0][r], sa[1][r]), fmaxf(sa[2][r], sa[3][r]));
            mx = rowmax16(mx);
            const float mn = fmaxf(m_r[r], mx);
            const float alpha = __expf(m_r[r] - mn);
            m_r[r] = mn;
            _Float16* pp = &Ps[wv][(fr + r) * 68 + fm];
            pp[0]  = (_Float16)__expf(sa[0][r] - mn);
            pp[16] = (_Float16)__expf(sa[1][r] - mn);
            pp[32] = (_Float16)__expf(sa[2][r] - mn);
            pp[48] = (_Float16)__expf(sa[3][r] - mn);
            lacc[r] *= alpha;
            O[0][r] *= alpha; O[1][r] *= alpha; O[2][r] *= alpha; O[3][r] *= alpha;
        }
        // Ps is wave-private: lgkmcnt ordering suffices, no barrier

        // ---- O += P V, l += P 1 : 10 MFMAs ----
        #pragma unroll
        for (int ch = 0; ch < 2; ++ch) {
            const half8 pa = *reinterpret_cast<const half8*>(&Ps[wv][fm * 68 + ch * 32 + fk]);
            lacc = __builtin_amdgcn_mfma_f32_16x16x32_f16(pa, ones, lacc, 0, 0, 0);
            #pragma unroll
            for (int ht = 0; ht < 4; ++ht) {
                const half8 vbf = *reinterpret_cast<const half8*>(&Vb[cur][(ht * 2 + ch) * 512 + pQ]);
                O[ht] = __builtin_amdgcn_mfma_f32_16x16x32_f16(pa, vbf, O[ht], 0, 0, 0);
            }
        }
    }

    // ---- epilogue: segment partial (unnormalized O, m, l) ----
    #pragma unroll
    for (int r = 0; r < 4; ++r) {
        const int grow = b * TT + it * 64 + wv * 16 + fr + r;
        if (s == 0) {
            #pragma unroll
            for (int ht = 0; ht < 4; ++ht)
                out[(size_t)grow * HH + ht * 16 + fm] = O[ht][r];
        } else {
            #pragma unroll
            for (int ht = 0; ht < 4; ++ht)
                Op[((size_t)(s - 1) * MM + grow) * HH + ht * 16 + fm] = (_Float16)O[ht][r];
        }
        if (fm == 0) {
            ml[((size_t)s * MM + grow) * 2 + 0] = m_r[r];
            ml[((size_t)s * MM + grow) * 2 + 1] = lacc[r];
        }
    }
}

// ---------------------------------------------------------------------------
// Kernel 3: flash-decode combine of the 3 segment partials.
// ---------------------------------------------------------------------------
__global__ __launch_bounds__(256)
void combine(float* __restrict__ out, const _Float16* __restrict__ Op,
             const float* __restrict__ ml)
{
    const int tid  = threadIdx.x;
    const int grow = blockIdx.x * 64 + (tid >> 2);
    const int c0   = (tid & 3) * 16;

    const float m0 = ml[(size_t)grow * 2 + 0];
    const float l0 = ml[(size_t)grow * 2 + 1];
    const float m1 = ml[((size_t)MM + grow) * 2 + 0];
    const float l1 = ml[((size_t)MM + grow) * 2 + 1];
    const float m2 = ml[((size_t)2 * MM + grow) * 2 + 0];
    const float l2 = ml[((size_t)2 * MM + grow) * 2 + 1];

    const float M  = fmaxf(m0, fmaxf(m1, m2));
    const float w0 = __expf(m0 - M);
    const float w1 = __expf(m1 - M);
    const float w2 = __expf(m2 - M);
    const float inv = 1.0f / (w0 * l0 + w1 * l1 + w2 * l2);

    #pragma unroll
    for (int i = 0; i < 16; i += 4) {
        float4 o0 = *reinterpret_cast<float4*>(&out[(size_t)grow * HH + c0 + i]);
        const half4 h1 = *reinterpret_cast<const half4*>(&Op[(size_t)grow * HH + c0 + i]);
        const half4 h2 = *reinterpret_cast<const half4*>(&Op[(size_t)MM * HH + (size_t)grow * HH + c0 + i]);
        o0.x = (w0 * o0.x + w1 * (float)h1[0] + w2 * (float)h2[0]) * inv;
        o0.y = (w0 * o0.y + w1 * (float)h1[1] + w2 * (float)h2[1]) * inv;
        o0.z = (w0 * o0.z + w1 * (float)h1[2] + w2 * (float)h2[2]) * inv;
        o0.w = (w0 * o0.w + w1 * (float)h1[3] + w2 * (float)h2[3]) * inv;
        *reinterpret_cast<float4*>(&out[(size_t)grow * HH + c0 + i]) = o0;
    }
}

// ---------------------------------------------------------------------------
extern "C" void kernel_launch(void* const* d_in, const int* in_sizes, int n_in,
                              void* d_out, int out_size, void* d_ws, size_t ws_size,
                              hipStream_t stream)
{
    (void)in_sizes; (void)n_in; (void)out_size; (void)ws_size;

    const float* x  = (const float*)d_in[0];
    const float* Wk = (const float*)d_in[1];
    const float* Wq = (const float*)d_in[2];
    const float* Wv = (const float*)d_in[3];
    float* out = (float*)d_out;

    _Float16* base = (_Float16*)d_ws;
    _Float16* q16 = base;                                  // MM*HH halves
    _Float16* Kp  = base + (size_t)MM * HH;                // MM*HH
    _Float16* Vp  = base + (size_t)2 * MM * HH;            // MM*HH
    _Float16* Wp  = base + (size_t)3 * MM * HH;            // 192*1024
    _Float16* Op  = Wp + 192 * 1024;                       // 2*MM*HH
    float*    ml  = (float*)(Op + (size_t)2 * MM * HH);    // 3*MM*2 floats

    w_pack<<<dim3(96), dim3(256), 0, stream>>>(Wk, Wq, Wv, Wp);
    qkv8<<<dim3(512), dim3(256), 0, stream>>>(x, Wp, q16, Kp, Vp);
    attn8<<<dim3(768), dim3(256), 0, stream>>>(q16, Kp, Vp, out, Op, ml);
    combine<<<dim3(256), dim3(256), 0, stream>>>(out, Op, ml);
}